// Round 8
// baseline (1249.833 us; speedup 1.0000x reference)
//
#include <hip/hip_runtime.h>

#define NN 100000

typedef __attribute__((ext_vector_type(8))) __bf16 bf16x8;
typedef __attribute__((ext_vector_type(8))) unsigned short ushort8v;
typedef __attribute__((ext_vector_type(4))) float f32x4;

__device__ __forceinline__ float bf2f(unsigned short u) {
    union { unsigned int ui; float f; } c;
    c.ui = ((unsigned int)u) << 16;
    return c.f;
}

__device__ __forceinline__ unsigned short f2bf(float f) {
    union { float ff; unsigned int ui; } c;
    c.ff = f;
    unsigned int u = c.ui;
    u += 0x7FFFu + ((u >> 16) & 1u);   // round-to-nearest-even
    return (unsigned short)(u >> 16);
}

// truncation split: x = hi + resid, hi = bf16-truncate(x)
__device__ __forceinline__ unsigned short trunc_hi(float x, float& resid) {
    union { float f; unsigned int u; } c, h;
    c.f = x;
    h.u = c.u & 0xFFFF0000u;
    resid = x - h.f;
    return (unsigned short)(c.u >> 16);
}

__device__ __forceinline__ unsigned short trunc_bits(float x) {
    union { float f; unsigned int u; } c;
    c.f = x;
    return (unsigned short)(c.u >> 16);
}

// async global->LDS, 16B per lane; LDS dst is wave-uniform base + lane*16 (HW).
__device__ __forceinline__ void gload_lds16(const void* g, void* l) {
    void* gnc = (void*)g;
    __builtin_amdgcn_global_load_lds((__attribute__((address_space(1))) void*)gnc,
                                     (__attribute__((address_space(3))) void*)l,
                                     16, 0, 0);
}

__global__ void MultiTaskGCN_37623913513359_kernel() {}

// flags[0]: edge index format, 1 = int64, 0 = int32
// flags[1]: float dtype, 1 = bf16-backed, 0 = fp32-backed
__global__ void probe_fmt(const int* ei, const unsigned short* x, int* flags) {
    if (blockIdx.x != 0 || threadIdx.x >= 64) return;
    int lane = threadIdx.x & 63;
    int any = ei[2 * lane + 1];
    unsigned long long b64 = __ballot(any != 0);
    int bad = 0;
#pragma unroll
    for (int r = 0; r < 8; ++r) {
        int i = r * 64 + lane;      // i < 512
        float v = bf2f(x[2 * i]);
        float av = v < 0.0f ? -v : v;
        if (!(v == v) || av > 1.0e6f) bad = 1;
    }
    unsigned long long bb = __ballot(bad != 0);
    if (lane == 0) {
        flags[0] = (b64 == 0) ? 1 : 0;
        flags[1] = (bb == 0) ? 1 : 0;
    }
}

__device__ __forceinline__ int edge_src(const int* ei, int is64, int e) {
    if (is64) return ei[2 * e];
    return ei[e];
}
__device__ __forceinline__ int edge_dst(const int* ei, int is64, int e, int E) {
    if (is64) return ei[2 * (E + e)];
    return ei[E + e];
}

__device__ __forceinline__ float load_f(const void* p, int dt, size_t i) {
    if (dt) return bf2f(((const unsigned short*)p)[i]);
    return ((const float*)p)[i];
}

__global__ __launch_bounds__(256) void count_deg_i(const int* ei, const int* flags,
                                                   int* degi, int E) {
    int t = blockIdx.x * 256 + threadIdx.x;
    if (t >= E) return;
    int is64 = flags[0];
    int s = edge_src(ei, is64, t);
    int d = edge_dst(ei, is64, t, E);
    if (((unsigned)s) >= NN || ((unsigned)d) >= NN) return;
    atomicAdd(&degi[d], 1);
}

__global__ __launch_bounds__(256) void make_dinv(const int* degi, float* dinv) {
    int i = blockIdx.x * 256 + threadIdx.x;
    if (i < NN) dinv[i] = rsqrtf((float)degi[i] + 1.0f);   // +1 self loop
}

// single-block exclusive scan of degi -> rowptr (NN+1 entries)
__global__ __launch_bounds__(1024) void scan_rowptr(const int* degi, int* rowptr) {
    __shared__ int part[1024];
    int tid = threadIdx.x;
    const int chunk = (NN + 1023) / 1024;   // 98
    int base = tid * chunk;
    int s = 0;
    for (int j = 0; j < chunk; ++j) {
        int i = base + j;
        if (i < NN) s += degi[i];
    }
    part[tid] = s;
    __syncthreads();
    for (int off = 1; off < 1024; off <<= 1) {
        int v = (tid >= off) ? part[tid - off] : 0;
        __syncthreads();
        part[tid] += v;
        __syncthreads();
    }
    int run = (tid == 0) ? 0 : part[tid - 1];
    for (int j = 0; j < chunk; ++j) {
        int i = base + j;
        if (i < NN) {
            rowptr[i] = run;
            run += degi[i];
        }
    }
    if (tid == 1023) rowptr[NN] = part[1023];
}

// fill CSR: packed entry = (w_bits << 32) | src
__global__ __launch_bounds__(256) void fill_csr(const int* ei, const int* flags,
                                                const float* dinv, const int* rowptr,
                                                int* cursor, unsigned long long* csr,
                                                int E) {
    int t = blockIdx.x * 256 + threadIdx.x;
    if (t >= E) return;
    int is64 = flags[0];
    int s = edge_src(ei, is64, t);
    int d = edge_dst(ei, is64, t, E);
    if (((unsigned)s) >= NN || ((unsigned)d) >= NN) return;
    int pos = rowptr[d] + atomicAdd(&cursor[d], 1);
    float w = dinv[s] * dinv[d];
    union { float ff; unsigned int ui; } c;
    c.ff = w;
    csr[pos] = ((unsigned long long)c.ui << 32) | (unsigned int)s;
}

// W1 (row-major [512][256], fp32 or bf16) -> W1T hi/lo bf16 [256 n][512 k]
__global__ __launch_bounds__(256) void prep_w1t(const void* W1, const int* flags,
                                                unsigned short* hi, unsigned short* lo) {
    int t = blockIdx.x * 256 + threadIdx.x;
    if (t >= 256 * 512) return;
    int n = t >> 9, k = t & 511;
    float v = load_f(W1, flags[1], (size_t)k * 256 + n);
    float r;
    hi[t] = trunc_hi(v, r);
    lo[t] = trunc_bits(r);
}

// [Wc | Wk | Wd | 0] -> WcatT hi/lo bf16 [64 n][256 k]
__global__ __launch_bounds__(256) void prep_wcat(const void* Wc, const void* Wk,
                                                 const void* Wd, const int* flags,
                                                 unsigned short* hi, unsigned short* lo) {
    int t = blockIdx.x * 256 + threadIdx.x;
    if (t >= 64 * 256) return;
    int n = t >> 8, k = t & 255;
    int dt = flags[1];
    float v = 0.0f;
    if (n < 40) v = load_f(Wc, dt, (size_t)k * 40 + n);
    else if (n < 56) v = load_f(Wk, dt, (size_t)k * 16 + (n - 40));
    else if (n == 56) v = load_f(Wd, dt, k);
    float r;
    hi[t] = trunc_hi(v, r);
    lo[t] = trunc_bits(r);
}

// ---------------- MFMA GEMM: global_load_lds B + in-kernel-split A ----------------

template<int BN, int NF>
__global__ __launch_bounds__(256, 3) void gemm_gl(const void* A,
                                                  const unsigned short* BTh,
                                                  const unsigned short* BTl,
                                                  unsigned short* C,
                                                  int M, int N, int K,
                                                  const int* flags, int amode) {
    constexpr int BM = 128;
    constexpr int HB = BN / 64;         // B col-halves
    __shared__ ushort8v smem[4 * BM + 4 * BM + 4 * BN + 4 * BN];
    ushort8v* Ash = smem;
    ushort8v* Asl = smem + 4 * BM;
    ushort8v* Bsh = smem + 8 * BM;
    ushort8v* Bsl = smem + 8 * BM + 4 * BN;

    const int tid = threadIdx.x;
    const int lane = tid & 63;
    const int wid = tid >> 6;
    const int wm = wid >> 1;
    const int wn = wid & 1;
    const int dt = flags[1];

    const int alo = (amode == 0 && dt == 0) ? 1 : 0;   // fp32 A: split path
    const int blo = (dt == 0) ? 1 : 0;

    const int m0 = blockIdx.x * BM;
    const int n0 = blockIdx.y * BN;

    f32x4 zero = {0.0f, 0.0f, 0.0f, 0.0f};
    f32x4 acc[4][NF];
#pragma unroll
    for (int i = 0; i < 4; ++i)
#pragma unroll
        for (int j = 0; j < NF; ++j) acc[i][j] = zero;

    const float* Af = (const float*)A;
    const unsigned short* Ab16 = (const unsigned short*)A;

    const int nT = K >> 5;              // K-steps of 32
    for (int t = 0; t < nT; ++t) {
        const int k0 = t << 5;
        // stage B via global_load_lds (4*HB slots over 4 waves)
        for (int q = wid; q < 4 * HB; q += 4) {
            int kg = q / HB, hf = q % HB;
            int col = n0 + hf * 64 + lane;
            gload_lds16(BTh + (size_t)col * K + k0 + kg * 8, Bsh + kg * BN + hf * 64);
            if (blo) gload_lds16(BTl + (size_t)col * K + k0 + kg * 8, Bsl + kg * BN + hf * 64);
        }
        // stage A
        if (alo) {
            // fp32: reg-load both subtiles, split, ds_write
            f32x4 ra[2][2];
#pragma unroll
            for (int u = 0; u < 2; ++u) {
                int q = wid + u * 4;
                int kg = q >> 1, hf = q & 1;
                int row = m0 + hf * 64 + lane;
                if (row >= M) row = M - 1;
                const float* ap = Af + (size_t)row * K + k0 + kg * 8;
                ra[u][0] = *(const f32x4*)ap;
                ra[u][1] = *(const f32x4*)(ap + 4);
            }
#pragma unroll
            for (int u = 0; u < 2; ++u) {
                int q = wid + u * 4;
                int kg = q >> 1, hf = q & 1;
                ushort8v h, l;
                float r;
#pragma unroll
                for (int j = 0; j < 4; ++j) {
                    h[j] = trunc_hi(ra[u][0][j], r);
                    l[j] = trunc_bits(r);
                }
#pragma unroll
                for (int j = 0; j < 4; ++j) {
                    h[4 + j] = trunc_hi(ra[u][1][j], r);
                    l[4 + j] = trunc_bits(r);
                }
                Ash[kg * BM + hf * 64 + lane] = h;
                Asl[kg * BM + hf * 64 + lane] = l;
            }
        } else {
            // bf16: direct global_load_lds
            for (int q = wid; q < 8; q += 4) {
                int kg = q >> 1, hf = q & 1;
                int row = m0 + hf * 64 + lane;
                if (row >= M) row = M - 1;
                gload_lds16(Ab16 + (size_t)row * K + k0 + kg * 8, Ash + kg * BM + hf * 64);
            }
        }
        __syncthreads();   // drains vmcnt (lds-DMA) + lgkmcnt (ds_write)

        {
            const int lr = lane & 15;
            const int lk = lane >> 4;
            bf16x8 ah[4], al[4];
#pragma unroll
            for (int i = 0; i < 4; ++i) {
                ah[i] = *(const bf16x8*)&Ash[lk * BM + wm * 64 + i * 16 + lr];
                if (alo) al[i] = *(const bf16x8*)&Asl[lk * BM + wm * 64 + i * 16 + lr];
            }
            bf16x8 bh[NF], bl[NF];
#pragma unroll
            for (int j = 0; j < NF; ++j) {
                bh[j] = *(const bf16x8*)&Bsh[lk * BN + wn * (NF * 16) + j * 16 + lr];
                if (blo) bl[j] = *(const bf16x8*)&Bsl[lk * BN + wn * (NF * 16) + j * 16 + lr];
            }
#pragma unroll
            for (int i = 0; i < 4; ++i) {
#pragma unroll
                for (int j = 0; j < NF; ++j) {
                    acc[i][j] = __builtin_amdgcn_mfma_f32_16x16x32_bf16(ah[i], bh[j], acc[i][j], 0, 0, 0);
                    if (blo) acc[i][j] = __builtin_amdgcn_mfma_f32_16x16x32_bf16(ah[i], bl[j], acc[i][j], 0, 0, 0);
                    if (alo) acc[i][j] = __builtin_amdgcn_mfma_f32_16x16x32_bf16(al[i], bh[j], acc[i][j], 0, 0, 0);
                }
            }
        }
        __syncthreads();
    }

    // epilogue: acc -> LDS [BM][BN] bf16 -> coalesced 16B stores
    unsigned short* cs = (unsigned short*)smem;
    const int lr = lane & 15;
    const int lq = lane >> 4;
#pragma unroll
    for (int i = 0; i < 4; ++i) {
#pragma unroll
        for (int j = 0; j < NF; ++j) {
#pragma unroll
            for (int rr = 0; rr < 4; ++rr) {
                int row = wm * 64 + i * 16 + lq * 4 + rr;
                int col = wn * (NF * 16) + j * 16 + lr;
                cs[row * BN + col] = f2bf(acc[i][j][rr]);
            }
        }
    }
    __syncthreads();
    constexpr int TOTAL = BM * BN;
#pragma unroll
    for (int base = 0; base < TOTAL; base += 2048) {
        int idx = base + tid * 8;
        int r = idx / BN;
        int c = idx % BN;
        int grow = m0 + r;
        if (grow < M) {
            *(ushort8v*)(C + (size_t)grow * N + n0 + c) = *(const ushort8v*)(cs + idx);
        }
    }
}

// layer-1 aggregation by pull + fused epilogue: one wave per destination node.
// 4-deep unrolled edge loop. NT hints: csr stream + hb output marked non-temporal
// so they don't evict the 32x-reused xwb rows (127MB working set vs 256MB L3).
__global__ __launch_bounds__(256) void gather_h(const int* rowptr,
                                                const unsigned long long* csr,
                                                const unsigned short* xwb,
                                                const void* b1,
                                                const float* dinv,
                                                const int* flags,
                                                unsigned short* hb) {
    int node = (blockIdx.x * 256 + threadIdx.x) >> 6;
    int lane = threadIdx.x & 63;
    if (node >= NN) return;
    int beg = rowptr[node], end = rowptr[node + 1];
    const unsigned short* xp = xwb + (size_t)lane * 4;

    float a0[4] = {0.f, 0.f, 0.f, 0.f};
    float a1[4] = {0.f, 0.f, 0.f, 0.f};
    float a2[4] = {0.f, 0.f, 0.f, 0.f};
    float a3[4] = {0.f, 0.f, 0.f, 0.f};

    int e = beg;
    for (; e + 4 <= end; e += 4) {
        unsigned long long p0 = __builtin_nontemporal_load(csr + e + 0);
        unsigned long long p1 = __builtin_nontemporal_load(csr + e + 1);
        unsigned long long p2 = __builtin_nontemporal_load(csr + e + 2);
        unsigned long long p3 = __builtin_nontemporal_load(csr + e + 3);
        unsigned long long v0 = *(const unsigned long long*)(xp + ((size_t)(unsigned int)p0) * 256);
        unsigned long long v1 = *(const unsigned long long*)(xp + ((size_t)(unsigned int)p1) * 256);
        unsigned long long v2 = *(const unsigned long long*)(xp + ((size_t)(unsigned int)p2) * 256);
        unsigned long long v3 = *(const unsigned long long*)(xp + ((size_t)(unsigned int)p3) * 256);
        union { unsigned int ui; float ff; } w0, w1, w2, w3;
        w0.ui = (unsigned int)(p0 >> 32);
        w1.ui = (unsigned int)(p1 >> 32);
        w2.ui = (unsigned int)(p2 >> 32);
        w3.ui = (unsigned int)(p3 >> 32);
        a0[0] += w0.ff * bf2f((unsigned short)v0);
        a0[1] += w0.ff * bf2f((unsigned short)(v0 >> 16));
        a0[2] += w0.ff * bf2f((unsigned short)(v0 >> 32));
        a0[3] += w0.ff * bf2f((unsigned short)(v0 >> 48));
        a1[0] += w1.ff * bf2f((unsigned short)v1);
        a1[1] += w1.ff * bf2f((unsigned short)(v1 >> 16));
        a1[2] += w1.ff * bf2f((unsigned short)(v1 >> 32));
        a1[3] += w1.ff * bf2f((unsigned short)(v1 >> 48));
        a2[0] += w2.ff * bf2f((unsigned short)v2);
        a2[1] += w2.ff * bf2f((unsigned short)(v2 >> 16));
        a2[2] += w2.ff * bf2f((unsigned short)(v2 >> 32));
        a2[3] += w2.ff * bf2f((unsigned short)(v2 >> 48));
        a3[0] += w3.ff * bf2f((unsigned short)v3);
        a3[1] += w3.ff * bf2f((unsigned short)(v3 >> 16));
        a3[2] += w3.ff * bf2f((unsigned short)(v3 >> 32));
        a3[3] += w3.ff * bf2f((unsigned short)(v3 >> 48));
    }
    for (; e < end; ++e) {
        unsigned long long p = __builtin_nontemporal_load(csr + e);
        union { unsigned int ui; float ff; } c;
        c.ui = (unsigned int)(p >> 32);
        unsigned long long v = *(const unsigned long long*)(xp + ((size_t)(unsigned int)p) * 256);
        a0[0] += c.ff * bf2f((unsigned short)v);
        a0[1] += c.ff * bf2f((unsigned short)(v >> 16));
        a0[2] += c.ff * bf2f((unsigned short)(v >> 32));
        a0[3] += c.ff * bf2f((unsigned short)(v >> 48));
    }

    int dt = flags[1];
    float di = dinv[node];
    float sl = di * di;
    size_t base = (size_t)node * 256 + lane * 4;
    unsigned long long v = *(const unsigned long long*)(xwb + base);
    float r0 = sl * bf2f((unsigned short)v)         + (a0[0] + a1[0]) + (a2[0] + a3[0]) + load_f(b1, dt, lane * 4 + 0);
    float r1 = sl * bf2f((unsigned short)(v >> 16)) + (a0[1] + a1[1]) + (a2[1] + a3[1]) + load_f(b1, dt, lane * 4 + 1);
    float r2 = sl * bf2f((unsigned short)(v >> 32)) + (a0[2] + a1[2]) + (a2[2] + a3[2]) + load_f(b1, dt, lane * 4 + 2);
    float r3 = sl * bf2f((unsigned short)(v >> 48)) + (a0[3] + a1[3]) + (a2[3] + a3[3]) + load_f(b1, dt, lane * 4 + 3);
    if (r0 < 0.f) r0 = 0.f;
    if (r1 < 0.f) r1 = 0.f;
    if (r2 < 0.f) r2 = 0.f;
    if (r3 < 0.f) r3 = 0.f;
    unsigned long long o = (unsigned long long)f2bf(r0)
                         | ((unsigned long long)f2bf(r1) << 16)
                         | ((unsigned long long)f2bf(r2) << 32)
                         | ((unsigned long long)f2bf(r3) << 48);
    __builtin_nontemporal_store(o, (unsigned long long*)(hb + base));
}

// layer-2 aggregation: one wave per node; lane group grp=lane>>4 takes edge e+grp,
// each lane covers 4 cols (8B). 4 quad-loads/iter = 16 edges in flight.
// NT hints on csr stream + outputs (preserve L3 for hw2b).
__global__ __launch_bounds__(256) void gather_out(const int* rowptr,
                                                  const unsigned long long* csr,
                                                  const unsigned short* hw2b,
                                                  const void* bc, const void* bk,
                                                  const void* bd,
                                                  const float* dinv,
                                                  const int* flags,
                                                  void* outv) {
    int node = (blockIdx.x * 256 + threadIdx.x) >> 6;
    int lane = threadIdx.x & 63;
    if (node >= NN) return;
    int beg = rowptr[node], end = rowptr[node + 1];
    int grp = lane >> 4;
    int sub = lane & 15;
    const unsigned short* hp = hw2b + (size_t)sub * 4;

    float acc[4] = {0.f, 0.f, 0.f, 0.f};

    int e = beg;
    for (; e + 16 <= end; e += 16) {
        unsigned long long p0 = __builtin_nontemporal_load(csr + e + grp);
        unsigned long long p1 = __builtin_nontemporal_load(csr + e + 4 + grp);
        unsigned long long p2 = __builtin_nontemporal_load(csr + e + 8 + grp);
        unsigned long long p3 = __builtin_nontemporal_load(csr + e + 12 + grp);
        unsigned long long v0 = *(const unsigned long long*)(hp + ((size_t)(unsigned int)p0) * 64);
        unsigned long long v1 = *(const unsigned long long*)(hp + ((size_t)(unsigned int)p1) * 64);
        unsigned long long v2 = *(const unsigned long long*)(hp + ((size_t)(unsigned int)p2) * 64);
        unsigned long long v3 = *(const unsigned long long*)(hp + ((size_t)(unsigned int)p3) * 64);
        union { unsigned int ui; float ff; } w0, w1, w2, w3;
        w0.ui = (unsigned int)(p0 >> 32);
        w1.ui = (unsigned int)(p1 >> 32);
        w2.ui = (unsigned int)(p2 >> 32);
        w3.ui = (unsigned int)(p3 >> 32);
#pragma unroll
        for (int j = 0; j < 4; ++j) acc[j] += w0.ff * bf2f((unsigned short)(v0 >> (16 * j)));
#pragma unroll
        for (int j = 0; j < 4; ++j) acc[j] += w1.ff * bf2f((unsigned short)(v1 >> (16 * j)));
#pragma unroll
        for (int j = 0; j < 4; ++j) acc[j] += w2.ff * bf2f((unsigned short)(v2 >> (16 * j)));
#pragma unroll
        for (int j = 0; j < 4; ++j) acc[j] += w3.ff * bf2f((unsigned short)(v3 >> (16 * j)));
    }
    for (; e < end; e += 4) {
        int idx = e + grp;
        unsigned long long p = (idx < end) ? __builtin_nontemporal_load(csr + idx) : 0ull;
        union { unsigned int ui; float ff; } w;
        w.ui = (unsigned int)(p >> 32);
        unsigned long long v = *(const unsigned long long*)(hp + ((size_t)(unsigned int)p) * 64);
#pragma unroll
        for (int j = 0; j < 4; ++j) acc[j] += w.ff * bf2f((unsigned short)(v >> (16 * j)));
    }

#pragma unroll
    for (int j = 0; j < 4; ++j) {
        acc[j] += __shfl_xor(acc[j], 16, 64);
        acc[j] += __shfl_xor(acc[j], 32, 64);
    }

    if (lane >= 16) return;
    int dt = flags[1];
    float di = dinv[node];
    float sl = di * di;
#pragma unroll
    for (int j = 0; j < 4; ++j) {
        int c = sub * 4 + j;
        if (c >= 57) continue;
        float v = sl * bf2f(hw2b[(size_t)node * 64 + c]) + acc[j];
        size_t o;
        if (c < 40) {
            v += load_f(bc, dt, c);
            o = (size_t)node * 40 + c;
        } else if (c < 56) {
            v += load_f(bk, dt, c - 40);
            o = (size_t)NN * 40 + (size_t)node * 16 + (c - 40);
        } else {
            v += load_f(bd, dt, 0);
            o = (size_t)NN * 56 + node;
        }
        if (dt) __builtin_nontemporal_store(f2bf(v), (unsigned short*)outv + o);
        else __builtin_nontemporal_store(v, (float*)outv + o);
    }
}

extern "C" void kernel_launch(void* const* d_in, const int* in_sizes, int n_in,
                              void* d_out, int out_size, void* d_ws, size_t ws_size,
                              hipStream_t stream) {
    const void* x  = d_in[0];
    const int* ei  = (const int*)d_in[1];
    const void* W1 = d_in[2];
    const void* b1 = d_in[3];
    const void* Wc = d_in[4];
    const void* bc = d_in[5];
    const void* Wk = d_in[6];
    const void* bk = d_in[7];
    const void* Wd = d_in[8];
    const void* bd = d_in[9];

    int E = in_sizes[1] / 2;

    hipError_t herr = hipSuccess;
    hipError_t e;

    // workspace layout (256B-aligned offsets)
    char* ws = (char*)d_ws;
    size_t off = 0;
    int* flags = (int*)(ws + off);                      off += 256;
    float* dinv = (float*)(ws + off);                   off += 400128;
    int* rowptr = (int*)(ws + off);                     off += 400384;   // NN+1
    char* scr = ws + off;                               off += 800256;
    // scratch phase 1 (graph build): degi + cursor
    int* degi = (int*)scr;
    int* cursor = (int*)(scr + 400128);
    // scratch phase 2 (after fill_csr): split weight tables
    unsigned short* w1t_hi = (unsigned short*)scr;
    unsigned short* w1t_lo = (unsigned short*)(scr + 262144);
    unsigned short* wct_hi = (unsigned short*)(scr + 524288);
    unsigned short* wct_lo = (unsigned short*)(scr + 557056);
    unsigned long long* csr = (unsigned long long*)(ws + off); off += (size_t)E * 8;
    unsigned short* xwb = (unsigned short*)(ws + off);  off += (size_t)NN * 256 * 2;
    unsigned short* hb = (unsigned short*)(ws + off);   off += (size_t)NN * 256 * 2;
    unsigned short* hw2b = (unsigned short*)(ws + off); off += (size_t)NN * 64 * 2;

    int ws_bad = (off > ws_size) ? 1 : 0;

    if (!ws_bad) {
        e = hipMemsetAsync(degi, 0, (size_t)NN * 4, stream);
        if (herr == hipSuccess && e != hipSuccess) herr = e;
        e = hipMemsetAsync(cursor, 0, (size_t)NN * 4, stream);
        if (herr == hipSuccess && e != hipSuccess) herr = e;

        probe_fmt<<<1, 64, 0, stream>>>(ei, (const unsigned short*)x, flags);
        count_deg_i<<<(E + 255) / 256, 256, 0, stream>>>(ei, flags, degi, E);
        make_dinv<<<(NN + 255) / 256, 256, 0, stream>>>(degi, dinv);
        scan_rowptr<<<1, 1024, 0, stream>>>(degi, rowptr);
        fill_csr<<<(E + 255) / 256, 256, 0, stream>>>(ei, flags, dinv, rowptr,
                                                      cursor, csr, E);

        // degi/cursor dead from here
        prep_w1t<<<512, 256, 0, stream>>>(W1, flags, w1t_hi, w1t_lo);
        prep_wcat<<<64, 256, 0, stream>>>(Wc, Wk, Wd, flags, wct_hi, wct_lo);

        // layer 1: xw = x @ W1   (M=100000, K=512, N=256), in-kernel A split
        {
            dim3 grid((NN + 127) / 128, 2);
            gemm_gl<128, 4><<<grid, 256, 0, stream>>>(x, w1t_hi, w1t_lo, xwb,
                                                      NN, 256, 512, flags, 0);
        }
        gather_h<<<(NN + 3) / 4, 256, 0, stream>>>(rowptr, csr, xwb, b1, dinv,
                                                   flags, hb);

        // layer 2: hw2 = h @ Wcat   (M=100000, K=256, N=64), A bf16 internal
        {
            dim3 grid((NN + 127) / 128, 1);
            gemm_gl<64, 2><<<grid, 256, 0, stream>>>(hb, wct_hi, wct_lo,
                                                     hw2b, NN, 64, 256, flags, 2);
        }
        gather_out<<<(NN + 3) / 4, 256, 0, stream>>>(rowptr, csr, hw2b, bc, bk, bd,
                                                     dinv, flags, d_out);
    }

    e = hipGetLastError();
    if (herr == hipSuccess && e != hipSuccess) herr = e;

    if (herr != hipSuccess) {
        (void)hipMemsetAsync(d_out, 0x41 + ((int)herr & 7), 128, stream);
    }
    if (ws_bad) {
        (void)hipMemsetAsync(d_out, 0x58, 128, stream);
    }
}